// Round 11
// baseline (97.714 us; speedup 1.0000x reference)
//
#include <hip/hip_runtime.h>
#include <hip/hip_fp16.h>

#define NPTS 100000
#define NJ 24
#define PDIM 64
#define LL 32
#define CC 16
#define JOINT_STRIDE (PDIM*LL*LL*CC)   /* 1<<20 floats = 4 MB per joint */
#define J4 (JOINT_STRIDE/4)
#define ID_STRIDE (LL*LL*CC)           /* 16384 floats */
#define RB 100                         /* reduce blocks */

/* transposed fp16 grid G[pn][y][x][j][c], half strides: */
#define TX_J   16
#define TX_X   (NJ*CC)        /* 384 */
#define TX_Y   (LL*NJ*CC)     /* 12288 */
#define TX_PN  (LL*LL*NJ*CC)  /* 393216 */
#define GRID_HALFS (3*TX_PN)  /* 1,179,648 halfs = 2.25 MB */

/* ws: floats [0,300) partials, [384,390) mi; fp16 grid at float idx 1024 */
#define WS_MI 384
#define WS_GRID_F 1024
#define WS_NEEDED ((size_t)WS_GRID_F*4 + (size_t)GRID_HALFS*2)

#define CVT_THREADS (3*LL*LL*NJ*2)     /* 147456: one per 8-half chunk */
#define CVT_BLOCKS  (CVT_THREADS/256)  /* 576 */

#define SPB 8                          /* sampler points per 128-thread block */
#define ROWQ (NJ*3*CC/4)               /* 288 f32x4 units per point row */
#define TQ 96                          /* f32x4 units per joint-group slice */

typedef float f32x4 __attribute__((ext_vector_type(4)));

/* blocks [0,RB): qp partial sums; blocks [RB, RB+CVT_BLOCKS): grid convert+transpose */
__global__ __launch_bounds__(256) void k_partial_cvt(const float* __restrict__ qp,
                                                     float* __restrict__ partial,
                                                     const float* __restrict__ px,
                                                     const float* __restrict__ py,
                                                     const float* __restrict__ pz,
                                                     const int* __restrict__ idp,
                                                     __half* __restrict__ gh) {
    const int tid = threadIdx.x;
    if (blockIdx.x >= RB) {
        /* t -> (pn, y, x, j, c8); src [pn][j][y][x][c] f32 -> dst [pn][y][x][j][c] fp16 */
        const int t    = (blockIdx.x - RB) * 256 + tid;
        const int c8   = t & 1;
        const int j    = (t >> 1) % NJ;
        const int rest = (t >> 1) / NJ;
        const int x    = rest & 31;
        const int y    = (rest >> 5) & 31;
        const int pn   = rest >> 10;
        const float* src = (pn == 0 ? px : pn == 1 ? py : pz)
                         + (size_t)(*idp) * ID_STRIDE + (size_t)j * JOINT_STRIDE
                         + (y * LL + x) * CC + c8 * 8;
        const f32x4 a = *(const f32x4*)src;
        const f32x4 b = *(const f32x4*)(src + 4);
        __half2 h0 = __float22half2_rn(make_float2(a.x, a.y));
        __half2 h1 = __float22half2_rn(make_float2(a.z, a.w));
        __half2 h2 = __float22half2_rn(make_float2(b.x, b.y));
        __half2 h3 = __float22half2_rn(make_float2(b.z, b.w));
        uint4 o;
        o.x = __builtin_bit_cast(unsigned int, h0);
        o.y = __builtin_bit_cast(unsigned int, h1);
        o.z = __builtin_bit_cast(unsigned int, h2);
        o.w = __builtin_bit_cast(unsigned int, h3);
        *(uint4*)(gh + (size_t)pn * TX_PN + y * TX_Y + x * TX_X + j * TX_J + c8 * 8) = o;
        return;
    }
    __shared__ float sm[3][256];
    float s0 = 0.f, s1 = 0.f, s2 = 0.f;
    for (int n = blockIdx.x * 256 + tid; n < NPTS; n += RB * 256) {
        s0 += qp[n * 3 + 0];
        s1 += qp[n * 3 + 1];
        s2 += qp[n * 3 + 2];
    }
    sm[0][tid] = s0; sm[1][tid] = s1; sm[2][tid] = s2;
    __syncthreads();
    for (int s = 128; s > 0; s >>= 1) {
        if (tid < s) {
            sm[0][tid] += sm[0][tid + s];
            sm[1][tid] += sm[1][tid + s];
            sm[2][tid] += sm[2][tid + s];
        }
        __syncthreads();
    }
    if (tid == 0) {
        partial[blockIdx.x * 3 + 0] = sm[0][0];
        partial[blockIdx.x * 3 + 1] = sm[1][0];
        partial[blockIdx.x * 3 + 2] = sm[2][0];
    }
}

/* fallback-path final reduce (only used when ws too small) */
__global__ __launch_bounds__(256) void k_final(const float* __restrict__ partial,
                                               const float* __restrict__ scale,
                                               float* __restrict__ mi) {
    __shared__ float sm[3][256];
    int tid = threadIdx.x;
    float s0 = 0.f, s1 = 0.f, s2 = 0.f;
    if (tid < RB) {
        s0 = partial[tid * 3 + 0];
        s1 = partial[tid * 3 + 1];
        s2 = partial[tid * 3 + 2];
    }
    sm[0][tid] = s0; sm[1][tid] = s1; sm[2][tid] = s2;
    __syncthreads();
    for (int s = 128; s > 0; s >>= 1) {
        if (tid < s) {
            sm[0][tid] += sm[0][tid + s];
            sm[1][tid] += sm[1][tid + s];
            sm[2][tid] += sm[2][tid + s];
        }
        __syncthreads();
    }
    if (tid == 0) {
        const float invn = 1.0f / (float)NPTS;
        mi[0] = sm[0][0] * invn;
        mi[1] = sm[1][0] * invn;
        mi[2] = sm[2][0] * invn;
        mi[3] = 1.0f / (scale[0] * 0.5f);
        mi[4] = 1.0f / (scale[1] * 0.5f);
        mi[5] = 1.0f / (scale[2] * 0.5f);
    }
}

/* Transposed-fp16 sampler, per-joint-group LDS staging (12.3 KB/block ->
   ~12 blocks/CU, 6 waves/SIMD). 128 threads = 8 points, 16 lanes/point.
   Output row factorizes by joint-group t: units [t*96,(t+1)*96) contiguous.
   Stage one t-slice, store it (6 x 256 B chunks/point), reuse buffer for
   t+1 -- wave-local LDS ordering, no barriers anywhere. */
__global__ __launch_bounds__(128) void k_sample_h(const float* __restrict__ qp,
                                                  const __half* __restrict__ gh,
                                                  const float* __restrict__ partial,
                                                  const float* __restrict__ scale,
                                                  float* __restrict__ out) {
    __shared__ f32x4 stg[SPB][TQ];   /* 12288 B */

    const int tid  = threadIdx.x;
    const int lane = tid & 63;
    const int pid  = tid >> 4;    /* point 0..7 */
    const int g    = tid & 15;
    const int p    = blockIdx.x * SPB + pid;   /* exact: 12500*8 = NPTS */

    /* in-wave mean reduction over 100 partials */
    float s0 = partial[lane * 3 + 0];
    float s1 = partial[lane * 3 + 1];
    float s2 = partial[lane * 3 + 2];
    if (lane + 64 < RB) {
        s0 += partial[(lane + 64) * 3 + 0];
        s1 += partial[(lane + 64) * 3 + 1];
        s2 += partial[(lane + 64) * 3 + 2];
    }
#pragma unroll
    for (int d = 1; d < 64; d <<= 1) {
        s0 += __shfl_xor(s0, d, 64);
        s1 += __shfl_xor(s1, d, 64);
        s2 += __shfl_xor(s2, d, 64);
    }
    const float invn = 1.0f / (float)NPTS;
    const float m0 = s0 * invn, m1 = s1 * invn, m2 = s2 * invn;
    const float i0 = 1.0f / (scale[0] * 0.5f);
    const float i1 = 1.0f / (scale[1] * 0.5f);
    const float i2 = 1.0f / (scale[2] * 0.5f);

    const float cx = (qp[p * 3 + 0] - m0) * i0;
    const float cy = (qp[p * 3 + 1] - m1) * i1;
    const float cz = (qp[p * 3 + 2] - m2) * i2;

    /* plane 0 (feat_x): gx=cy (W), gy=cx (H)
       plane 1 (feat_y): gx=cz,     gy=cy
       plane 2 (feat_z): gx=cx,     gy=cz  */
    const float gxs[3] = {cy, cz, cx};
    const float gys[3] = {cx, cy, cz};

    const int jhi  = g >> 1;         /* 0..7 */
    const int uch  = (g & 1) * 2;    /* unit offset for ch-half */
    const int ubase = jhi * 12 + uch;

    float w00[3], w01[3], w10[3], w11[3];
    const uint4 *c00[3], *c01[3], *c10[3], *c11[3];
#pragma unroll
    for (int pn = 0; pn < 3; ++pn) {
        float fx = fminf(fmaxf((gxs[pn] + 1.0f) * (0.5f * (LL - 1)), 0.0f), (float)(LL - 1));
        float fy = fminf(fmaxf((gys[pn] + 1.0f) * (0.5f * (LL - 1)), 0.0f), (float)(LL - 1));
        int x0 = (int)fx, y0 = (int)fy;
        float wx = fx - (float)x0, wy = fy - (float)y0;
        int x1 = min(x0 + 1, LL - 1), y1 = min(y0 + 1, LL - 1);
        w00[pn] = (1.f - wx) * (1.f - wy);
        w01[pn] = wx * (1.f - wy);
        w10[pn] = (1.f - wx) * wy;
        w11[pn] = wx * wy;
        const __half* pb = gh + (size_t)pn * TX_PN;
        c00[pn] = (const uint4*)(pb + y0 * TX_Y + x0 * TX_X) + g;
        c01[pn] = (const uint4*)(pb + y0 * TX_Y + x1 * TX_X) + g;
        c10[pn] = (const uint4*)(pb + y1 * TX_Y + x0 * TX_X) + g;
        c11[pn] = (const uint4*)(pb + y1 * TX_Y + x1 * TX_X) + g;
    }

    f32x4* outq = (f32x4*)out + (size_t)p * ROWQ + g;

#pragma unroll
    for (int t = 0; t < 3; ++t) {
#pragma unroll
        for (int pn = 0; pn < 3; ++pn) {
            const uint4 q00 = c00[pn][t * 16];
            const uint4 q01 = c01[pn][t * 16];
            const uint4 q10 = c10[pn][t * 16];
            const uint4 q11 = c11[pn][t * 16];
            const float a00 = w00[pn], a01 = w01[pn], a10 = w10[pn], a11 = w11[pn];

            f32x4 rlo, rhi;
            {
                float2 a0 = __half22float2(__builtin_bit_cast(__half2, q00.x));
                float2 a1 = __half22float2(__builtin_bit_cast(__half2, q01.x));
                float2 a2 = __half22float2(__builtin_bit_cast(__half2, q10.x));
                float2 a3 = __half22float2(__builtin_bit_cast(__half2, q11.x));
                rlo.x = a00 * a0.x + a01 * a1.x + a10 * a2.x + a11 * a3.x;
                rlo.y = a00 * a0.y + a01 * a1.y + a10 * a2.y + a11 * a3.y;
                float2 b0 = __half22float2(__builtin_bit_cast(__half2, q00.y));
                float2 b1 = __half22float2(__builtin_bit_cast(__half2, q01.y));
                float2 b2 = __half22float2(__builtin_bit_cast(__half2, q10.y));
                float2 b3 = __half22float2(__builtin_bit_cast(__half2, q11.y));
                rlo.z = a00 * b0.x + a01 * b1.x + a10 * b2.x + a11 * b3.x;
                rlo.w = a00 * b0.y + a01 * b1.y + a10 * b2.y + a11 * b3.y;
                float2 c0 = __half22float2(__builtin_bit_cast(__half2, q00.z));
                float2 c1 = __half22float2(__builtin_bit_cast(__half2, q01.z));
                float2 c2 = __half22float2(__builtin_bit_cast(__half2, q10.z));
                float2 c3 = __half22float2(__builtin_bit_cast(__half2, q11.z));
                rhi.x = a00 * c0.x + a01 * c1.x + a10 * c2.x + a11 * c3.x;
                rhi.y = a00 * c0.y + a01 * c1.y + a10 * c2.y + a11 * c3.y;
                float2 d0 = __half22float2(__builtin_bit_cast(__half2, q00.w));
                float2 d1 = __half22float2(__builtin_bit_cast(__half2, q01.w));
                float2 d2 = __half22float2(__builtin_bit_cast(__half2, q10.w));
                float2 d3 = __half22float2(__builtin_bit_cast(__half2, q11.w));
                rhi.z = a00 * d0.x + a01 * d1.x + a10 * d2.x + a11 * d3.x;
                rhi.w = a00 * d0.y + a01 * d1.y + a10 * d2.y + a11 * d3.y;
            }
            const int u = ubase + pn * 4;
            stg[pid][u]     = rlo;
            stg[pid][u + 1] = rhi;
        }

        /* store slice t: 6 x 256 B sequential chunks per point (wave-local
           LDS visibility via lgkmcnt; no barrier) */
#pragma unroll
        for (int s = 0; s < 6; ++s) {
            __builtin_nontemporal_store(stg[pid][s * 16 + g], &outq[t * TQ + s * 16]);
        }
    }
}

/* f32 fallback (R4) if ws too small for the fp16 grid. */
__global__ __launch_bounds__(256) void k_sample_f(const float* __restrict__ qp,
                                                  const float* __restrict__ px,
                                                  const float* __restrict__ py,
                                                  const float* __restrict__ pz,
                                                  const float* __restrict__ mi,
                                                  const int* __restrict__ idp,
                                                  float* __restrict__ out) {
    const int tid  = threadIdx.x;
    const int wv   = tid >> 6;
    const int lane = tid & 63;
    const int pt   = lane >> 4;
    const int jg   = (lane >> 2) & 3;
    const int cq   = lane & 3;
    const int p    = blockIdx.x * 16 + wv * 4 + pt;

    const int id = *idp;
    const size_t sid = (size_t)id * ID_STRIDE;

    const float m0 = mi[0], m1 = mi[1], m2 = mi[2];
    const float i0 = mi[3], i1 = mi[4], i2 = mi[5];

    const float cx = (qp[p * 3 + 0] - m0) * i0;
    const float cy = (qp[p * 3 + 1] - m1) * i1;
    const float cz = (qp[p * 3 + 2] - m2) * i2;

    const float gxs[3] = {cy, cz, cx};
    const float gys[3] = {cx, cy, cz};
    const f32x4* base4[3] = {(const f32x4*)(px + sid),
                             (const f32x4*)(py + sid),
                             (const f32x4*)(pz + sid)};

    float w00[3], w01[3], w10[3], w11[3];
    int   v00[3], v01[3], v10[3], v11[3];
#pragma unroll
    for (int pn = 0; pn < 3; ++pn) {
        float fx = fminf(fmaxf((gxs[pn] + 1.0f) * (0.5f * (LL - 1)), 0.0f), (float)(LL - 1));
        float fy = fminf(fmaxf((gys[pn] + 1.0f) * (0.5f * (LL - 1)), 0.0f), (float)(LL - 1));
        int x0 = (int)fx, y0 = (int)fy;
        float wx = fx - (float)x0, wy = fy - (float)y0;
        int x1 = min(x0 + 1, LL - 1), y1 = min(y0 + 1, LL - 1);
        w00[pn] = (1.f - wx) * (1.f - wy);
        w01[pn] = wx * (1.f - wy);
        w10[pn] = (1.f - wx) * wy;
        w11[pn] = wx * wy;
        const int jb = jg * J4 + cq;
        v00[pn] = jb + (y0 * LL + x0) * 4;
        v01[pn] = jb + (y0 * LL + x1) * 4;
        v10[pn] = jb + (y1 * LL + x0) * 4;
        v11[pn] = jb + (y1 * LL + x1) * 4;
    }

    f32x4* outq = (f32x4*)out + (size_t)p * ROWQ + jg * 12 + cq;

#pragma unroll
    for (int pn = 0; pn < 3; ++pn) {
        const f32x4* bp = base4[pn];
        const float a00 = w00[pn], a01 = w01[pn], a10 = w10[pn], a11 = w11[pn];
        const int u00 = v00[pn], u01 = v01[pn], u10 = v10[pn], u11 = v11[pn];
#pragma unroll
        for (int jt = 0; jt < 6; ++jt) {
            const f32x4* bj = bp + (size_t)jt * 4 * J4;
            const f32x4 g00 = bj[u00];
            const f32x4 g01 = bj[u01];
            const f32x4 g10 = bj[u10];
            const f32x4 g11 = bj[u11];
            f32x4 r = a00 * g00 + a01 * g01 + a10 * g10 + a11 * g11;
            __builtin_nontemporal_store(r, &outq[jt * 48 + pn * 4]);
        }
    }
}

extern "C" void kernel_launch(void* const* d_in, const int* in_sizes, int n_in,
                              void* d_out, int out_size, void* d_ws, size_t ws_size,
                              hipStream_t stream) {
    const int*   idp   = (const int*)d_in[0];
    const float* qp    = (const float*)d_in[1];
    const float* scale = (const float*)d_in[2];
    const float* px    = (const float*)d_in[3];
    const float* py    = (const float*)d_in[4];
    const float* pz    = (const float*)d_in[5];
    float* out = (float*)d_out;
    float* ws  = (float*)d_ws;

    if (ws_size >= WS_NEEDED) {
        __half* gh = (__half*)(ws + WS_GRID_F);
        k_partial_cvt<<<RB + CVT_BLOCKS, 256, 0, stream>>>(qp, ws, px, py, pz, idp, gh);
        k_sample_h<<<NPTS / SPB, 128, 0, stream>>>(qp, gh, ws, scale, out);
    } else {
        k_partial_cvt<<<RB, 256, 0, stream>>>(qp, ws, px, py, pz, idp, (__half*)nullptr);
        k_final<<<1, 256, 0, stream>>>(ws, scale, ws + WS_MI);
        k_sample_f<<<NPTS / 16, 256, 0, stream>>>(qp, px, py, pz, ws + WS_MI, idp, out);
    }
}

// Round 12
// 91.719 us; speedup vs baseline: 1.0654x; 1.0654x over previous
//
#include <hip/hip_runtime.h>
#include <hip/hip_fp16.h>

#define NPTS 100000
#define NJ 24
#define PDIM 64
#define LL 32
#define CC 16
#define JOINT_STRIDE (PDIM*LL*LL*CC)   /* 1<<20 floats = 4 MB per joint */
#define J4 (JOINT_STRIDE/4)
#define ID_STRIDE (LL*LL*CC)           /* 16384 floats */
#define RB 100                         /* reduce blocks */

/* transposed fp16 grid G[pn][y][x][j][c], half strides: */
#define TX_J   16
#define TX_X   (NJ*CC)        /* 384 */
#define TX_Y   (LL*NJ*CC)     /* 12288 */
#define TX_PN  (LL*LL*NJ*CC)  /* 393216 */
#define GRID_HALFS (3*TX_PN)  /* 1,179,648 halfs = 2.25 MB */

/* ws: floats [0,300) partials, [384,390) mi; fp16 grid at float idx 1024 */
#define WS_MI 384
#define WS_GRID_F 1024
#define WS_NEEDED ((size_t)WS_GRID_F*4 + (size_t)GRID_HALFS*2)

#define CVT_THREADS (3*LL*LL*NJ*2)     /* 147456: one per 8-half chunk */
#define CVT_BLOCKS  (CVT_THREADS/256)  /* 576 */

#define SPB 8                          /* sampler points per 128-thread block */
#define ROWQ (NJ*3*CC/4)               /* 288 f32x4 units per point row */

typedef float f32x4 __attribute__((ext_vector_type(4)));

/* blocks [0,RB): qp partial sums; blocks [RB, RB+CVT_BLOCKS): grid convert+transpose */
__global__ __launch_bounds__(256) void k_partial_cvt(const float* __restrict__ qp,
                                                     float* __restrict__ partial,
                                                     const float* __restrict__ px,
                                                     const float* __restrict__ py,
                                                     const float* __restrict__ pz,
                                                     const int* __restrict__ idp,
                                                     __half* __restrict__ gh) {
    const int tid = threadIdx.x;
    if (blockIdx.x >= RB) {
        /* t -> (pn, y, x, j, c8); src [pn][j][y][x][c] f32 -> dst [pn][y][x][j][c] fp16 */
        const int t    = (blockIdx.x - RB) * 256 + tid;
        const int c8   = t & 1;
        const int j    = (t >> 1) % NJ;
        const int rest = (t >> 1) / NJ;
        const int x    = rest & 31;
        const int y    = (rest >> 5) & 31;
        const int pn   = rest >> 10;
        const float* src = (pn == 0 ? px : pn == 1 ? py : pz)
                         + (size_t)(*idp) * ID_STRIDE + (size_t)j * JOINT_STRIDE
                         + (y * LL + x) * CC + c8 * 8;
        const f32x4 a = *(const f32x4*)src;
        const f32x4 b = *(const f32x4*)(src + 4);
        __half2 h0 = __float22half2_rn(make_float2(a.x, a.y));
        __half2 h1 = __float22half2_rn(make_float2(a.z, a.w));
        __half2 h2 = __float22half2_rn(make_float2(b.x, b.y));
        __half2 h3 = __float22half2_rn(make_float2(b.z, b.w));
        uint4 o;
        o.x = __builtin_bit_cast(unsigned int, h0);
        o.y = __builtin_bit_cast(unsigned int, h1);
        o.z = __builtin_bit_cast(unsigned int, h2);
        o.w = __builtin_bit_cast(unsigned int, h3);
        *(uint4*)(gh + (size_t)pn * TX_PN + y * TX_Y + x * TX_X + j * TX_J + c8 * 8) = o;
        return;
    }
    __shared__ float sm[3][256];
    float s0 = 0.f, s1 = 0.f, s2 = 0.f;
    for (int n = blockIdx.x * 256 + tid; n < NPTS; n += RB * 256) {
        s0 += qp[n * 3 + 0];
        s1 += qp[n * 3 + 1];
        s2 += qp[n * 3 + 2];
    }
    sm[0][tid] = s0; sm[1][tid] = s1; sm[2][tid] = s2;
    __syncthreads();
    for (int s = 128; s > 0; s >>= 1) {
        if (tid < s) {
            sm[0][tid] += sm[0][tid + s];
            sm[1][tid] += sm[1][tid + s];
            sm[2][tid] += sm[2][tid + s];
        }
        __syncthreads();
    }
    if (tid == 0) {
        partial[blockIdx.x * 3 + 0] = sm[0][0];
        partial[blockIdx.x * 3 + 1] = sm[1][0];
        partial[blockIdx.x * 3 + 2] = sm[2][0];
    }
}

/* fallback-path final reduce (only used when ws too small) */
__global__ __launch_bounds__(256) void k_final(const float* __restrict__ partial,
                                               const float* __restrict__ scale,
                                               float* __restrict__ mi) {
    __shared__ float sm[3][256];
    int tid = threadIdx.x;
    float s0 = 0.f, s1 = 0.f, s2 = 0.f;
    if (tid < RB) {
        s0 = partial[tid * 3 + 0];
        s1 = partial[tid * 3 + 1];
        s2 = partial[tid * 3 + 2];
    }
    sm[0][tid] = s0; sm[1][tid] = s1; sm[2][tid] = s2;
    __syncthreads();
    for (int s = 128; s > 0; s >>= 1) {
        if (tid < s) {
            sm[0][tid] += sm[0][tid + s];
            sm[1][tid] += sm[1][tid + s];
            sm[2][tid] += sm[2][tid + s];
        }
        __syncthreads();
    }
    if (tid == 0) {
        const float invn = 1.0f / (float)NPTS;
        mi[0] = sm[0][0] * invn;
        mi[1] = sm[1][0] * invn;
        mi[2] = sm[2][0] * invn;
        mi[3] = 1.0f / (scale[0] * 0.5f);
        mi[4] = 1.0f / (scale[1] * 0.5f);
        mi[5] = 1.0f / (scale[2] * 0.5f);
    }
}

/* Transposed-fp16 sampler + wave-local LDS store staging, no barrier.
   Identical to R9 except stores use the default write-back policy
   (A/B vs nontemporal: fill kernel achieves 6.9 TB/s with regular stores). */
__global__ __launch_bounds__(128) void k_sample_h(const float* __restrict__ qp,
                                                  const __half* __restrict__ gh,
                                                  const float* __restrict__ partial,
                                                  const float* __restrict__ scale,
                                                  float* __restrict__ out) {
    __shared__ f32x4 stg[SPB][ROWQ];   /* 36864 B */

    const int tid  = threadIdx.x;
    const int lane = tid & 63;
    const int pid  = tid >> 4;    /* point 0..7 */
    const int g    = tid & 15;
    const int p    = blockIdx.x * SPB + pid;   /* exact: 12500*8 = NPTS */

    /* in-wave mean reduction over 100 partials */
    float s0 = partial[lane * 3 + 0];
    float s1 = partial[lane * 3 + 1];
    float s2 = partial[lane * 3 + 2];
    if (lane + 64 < RB) {
        s0 += partial[(lane + 64) * 3 + 0];
        s1 += partial[(lane + 64) * 3 + 1];
        s2 += partial[(lane + 64) * 3 + 2];
    }
#pragma unroll
    for (int d = 1; d < 64; d <<= 1) {
        s0 += __shfl_xor(s0, d, 64);
        s1 += __shfl_xor(s1, d, 64);
        s2 += __shfl_xor(s2, d, 64);
    }
    const float invn = 1.0f / (float)NPTS;
    const float m0 = s0 * invn, m1 = s1 * invn, m2 = s2 * invn;
    const float i0 = 1.0f / (scale[0] * 0.5f);
    const float i1 = 1.0f / (scale[1] * 0.5f);
    const float i2 = 1.0f / (scale[2] * 0.5f);

    const float cx = (qp[p * 3 + 0] - m0) * i0;
    const float cy = (qp[p * 3 + 1] - m1) * i1;
    const float cz = (qp[p * 3 + 2] - m2) * i2;

    /* plane 0 (feat_x): gx=cy (W), gy=cx (H)
       plane 1 (feat_y): gx=cz,     gy=cy
       plane 2 (feat_z): gx=cx,     gy=cz  */
    const float gxs[3] = {cy, cz, cx};
    const float gys[3] = {cx, cy, cz};

    const int jhi  = g >> 1;         /* 0..7 */
    const int uch  = (g & 1) * 2;    /* unit offset for ch-half */

#pragma unroll
    for (int pn = 0; pn < 3; ++pn) {
        float fx = fminf(fmaxf((gxs[pn] + 1.0f) * (0.5f * (LL - 1)), 0.0f), (float)(LL - 1));
        float fy = fminf(fmaxf((gys[pn] + 1.0f) * (0.5f * (LL - 1)), 0.0f), (float)(LL - 1));
        int x0 = (int)fx, y0 = (int)fy;
        float wx = fx - (float)x0, wy = fy - (float)y0;
        int x1 = min(x0 + 1, LL - 1), y1 = min(y0 + 1, LL - 1);
        const float w00 = (1.f - wx) * (1.f - wy);
        const float w01 = wx * (1.f - wy);
        const float w10 = (1.f - wx) * wy;
        const float w11 = wx * wy;

        const __half* pb = gh + (size_t)pn * TX_PN;
        const uint4* c00 = (const uint4*)(pb + y0 * TX_Y + x0 * TX_X) + g;
        const uint4* c01 = (const uint4*)(pb + y0 * TX_Y + x1 * TX_X) + g;
        const uint4* c10 = (const uint4*)(pb + y1 * TX_Y + x0 * TX_X) + g;
        const uint4* c11 = (const uint4*)(pb + y1 * TX_Y + x1 * TX_X) + g;

#pragma unroll
        for (int t = 0; t < 3; ++t) {
            const uint4 q00 = c00[t * 16];
            const uint4 q01 = c01[t * 16];
            const uint4 q10 = c10[t * 16];
            const uint4 q11 = c11[t * 16];

            f32x4 rlo, rhi;
            {
                float2 a0 = __half22float2(__builtin_bit_cast(__half2, q00.x));
                float2 a1 = __half22float2(__builtin_bit_cast(__half2, q01.x));
                float2 a2 = __half22float2(__builtin_bit_cast(__half2, q10.x));
                float2 a3 = __half22float2(__builtin_bit_cast(__half2, q11.x));
                rlo.x = w00 * a0.x + w01 * a1.x + w10 * a2.x + w11 * a3.x;
                rlo.y = w00 * a0.y + w01 * a1.y + w10 * a2.y + w11 * a3.y;
                float2 b0 = __half22float2(__builtin_bit_cast(__half2, q00.y));
                float2 b1 = __half22float2(__builtin_bit_cast(__half2, q01.y));
                float2 b2 = __half22float2(__builtin_bit_cast(__half2, q10.y));
                float2 b3 = __half22float2(__builtin_bit_cast(__half2, q11.y));
                rlo.z = w00 * b0.x + w01 * b1.x + w10 * b2.x + w11 * b3.x;
                rlo.w = w00 * b0.y + w01 * b1.y + w10 * b2.y + w11 * b3.y;
                float2 c0 = __half22float2(__builtin_bit_cast(__half2, q00.z));
                float2 c1 = __half22float2(__builtin_bit_cast(__half2, q01.z));
                float2 c2 = __half22float2(__builtin_bit_cast(__half2, q10.z));
                float2 c3 = __half22float2(__builtin_bit_cast(__half2, q11.z));
                rhi.x = w00 * c0.x + w01 * c1.x + w10 * c2.x + w11 * c3.x;
                rhi.y = w00 * c0.y + w01 * c1.y + w10 * c2.y + w11 * c3.y;
                float2 d0 = __half22float2(__builtin_bit_cast(__half2, q00.w));
                float2 d1 = __half22float2(__builtin_bit_cast(__half2, q01.w));
                float2 d2 = __half22float2(__builtin_bit_cast(__half2, q10.w));
                float2 d3 = __half22float2(__builtin_bit_cast(__half2, q11.w));
                rhi.z = w00 * d0.x + w01 * d1.x + w10 * d2.x + w11 * d3.x;
                rhi.w = w00 * d0.y + w01 * d1.y + w10 * d2.y + w11 * d3.y;
            }
            const int u = (t * 8 + jhi) * 12 + pn * 4 + uch;
            stg[pid][u]     = rlo;
            stg[pid][u + 1] = rhi;
        }
    }

    /* store phase: same-wave LDS visibility (lgkmcnt), no barrier needed.
       Sequential 256 B chunks per point, consecutive points. Regular
       write-back stores (A/B vs nt). */
    f32x4* outq = (f32x4*)out + (size_t)p * ROWQ + g;
#pragma unroll
    for (int s = 0; s < 18; ++s) {
        outq[s * 16] = stg[pid][s * 16 + g];
    }
}

/* f32 fallback (R4) if ws too small for the fp16 grid. */
__global__ __launch_bounds__(256) void k_sample_f(const float* __restrict__ qp,
                                                  const float* __restrict__ px,
                                                  const float* __restrict__ py,
                                                  const float* __restrict__ pz,
                                                  const float* __restrict__ mi,
                                                  const int* __restrict__ idp,
                                                  float* __restrict__ out) {
    const int tid  = threadIdx.x;
    const int wv   = tid >> 6;
    const int lane = tid & 63;
    const int pt   = lane >> 4;
    const int jg   = (lane >> 2) & 3;
    const int cq   = lane & 3;
    const int p    = blockIdx.x * 16 + wv * 4 + pt;

    const int id = *idp;
    const size_t sid = (size_t)id * ID_STRIDE;

    const float m0 = mi[0], m1 = mi[1], m2 = mi[2];
    const float i0 = mi[3], i1 = mi[4], i2 = mi[5];

    const float cx = (qp[p * 3 + 0] - m0) * i0;
    const float cy = (qp[p * 3 + 1] - m1) * i1;
    const float cz = (qp[p * 3 + 2] - m2) * i2;

    const float gxs[3] = {cy, cz, cx};
    const float gys[3] = {cx, cy, cz};
    const f32x4* base4[3] = {(const f32x4*)(px + sid),
                             (const f32x4*)(py + sid),
                             (const f32x4*)(pz + sid)};

    float w00[3], w01[3], w10[3], w11[3];
    int   v00[3], v01[3], v10[3], v11[3];
#pragma unroll
    for (int pn = 0; pn < 3; ++pn) {
        float fx = fminf(fmaxf((gxs[pn] + 1.0f) * (0.5f * (LL - 1)), 0.0f), (float)(LL - 1));
        float fy = fminf(fmaxf((gys[pn] + 1.0f) * (0.5f * (LL - 1)), 0.0f), (float)(LL - 1));
        int x0 = (int)fx, y0 = (int)fy;
        float wx = fx - (float)x0, wy = fy - (float)y0;
        int x1 = min(x0 + 1, LL - 1), y1 = min(y0 + 1, LL - 1);
        w00[pn] = (1.f - wx) * (1.f - wy);
        w01[pn] = wx * (1.f - wy);
        w10[pn] = (1.f - wx) * wy;
        w11[pn] = wx * wy;
        const int jb = jg * J4 + cq;
        v00[pn] = jb + (y0 * LL + x0) * 4;
        v01[pn] = jb + (y0 * LL + x1) * 4;
        v10[pn] = jb + (y1 * LL + x0) * 4;
        v11[pn] = jb + (y1 * LL + x1) * 4;
    }

    f32x4* outq = (f32x4*)out + (size_t)p * ROWQ + jg * 12 + cq;

#pragma unroll
    for (int pn = 0; pn < 3; ++pn) {
        const f32x4* bp = base4[pn];
        const float a00 = w00[pn], a01 = w01[pn], a10 = w10[pn], a11 = w11[pn];
        const int u00 = v00[pn], u01 = v01[pn], u10 = v10[pn], u11 = v11[pn];
#pragma unroll
        for (int jt = 0; jt < 6; ++jt) {
            const f32x4* bj = bp + (size_t)jt * 4 * J4;
            const f32x4 g00 = bj[u00];
            const f32x4 g01 = bj[u01];
            const f32x4 g10 = bj[u10];
            const f32x4 g11 = bj[u11];
            f32x4 r = a00 * g00 + a01 * g01 + a10 * g10 + a11 * g11;
            __builtin_nontemporal_store(r, &outq[jt * 48 + pn * 4]);
        }
    }
}

extern "C" void kernel_launch(void* const* d_in, const int* in_sizes, int n_in,
                              void* d_out, int out_size, void* d_ws, size_t ws_size,
                              hipStream_t stream) {
    const int*   idp   = (const int*)d_in[0];
    const float* qp    = (const float*)d_in[1];
    const float* scale = (const float*)d_in[2];
    const float* px    = (const float*)d_in[3];
    const float* py    = (const float*)d_in[4];
    const float* pz    = (const float*)d_in[5];
    float* out = (float*)d_out;
    float* ws  = (float*)d_ws;

    if (ws_size >= WS_NEEDED) {
        __half* gh = (__half*)(ws + WS_GRID_F);
        k_partial_cvt<<<RB + CVT_BLOCKS, 256, 0, stream>>>(qp, ws, px, py, pz, idp, gh);
        k_sample_h<<<NPTS / SPB, 128, 0, stream>>>(qp, gh, ws, scale, out);
    } else {
        k_partial_cvt<<<RB, 256, 0, stream>>>(qp, ws, px, py, pz, idp, (__half*)nullptr);
        k_final<<<1, 256, 0, stream>>>(ws, scale, ws + WS_MI);
        k_sample_f<<<NPTS / 16, 256, 0, stream>>>(qp, px, py, pz, ws + WS_MI, idp, out);
    }
}